// Round 14
// baseline (238.256 us; speedup 1.0000x reference)
//
#include <hip/hip_runtime.h>
#include <hip/hip_bf16.h>

#define NTOK 2048
#define HDIM 1024
#define DDIM 1024
#define NEXP 8
#define MBT 24   // max M-tiles: sum ceil(c_e/256) <= 16 + 7 = 23

typedef __bf16 bf16x8 __attribute__((ext_vector_type(8)));
typedef float f32x4 __attribute__((ext_vector_type(4)));
typedef float f32x2 __attribute__((ext_vector_type(2)));

__device__ __forceinline__ f32x4 mfma16(bf16x8 a, bf16x8 b, f32x4 c) {
  return __builtin_amdgcn_mfma_f32_16x16x32_bf16(a, b, c, 0, 0, 0);
}

__device__ __forceinline__ void async_copy16(const void* g, void* l) {
  __builtin_amdgcn_global_load_lds(
      (const __attribute__((address_space(1))) void*)g,
      (__attribute__((address_space(3))) void*)l, 16, 0, 0);
}

// -------- setup: router + zero `out` (for down's atomic combine). 512 blocks. ----------
__global__ __launch_bounds__(256) void setup_kernel(
    const float* __restrict__ x, const float* __restrict__ rw,
    __bf16* __restrict__ xb,
    unsigned int* __restrict__ top_pack, float2* __restrict__ top_w,
    float* __restrict__ out)
{
  f32x4 z = (f32x4){0.f, 0.f, 0.f, 0.f};
#pragma unroll
  for (int i = 0; i < 4; ++i)
    ((f32x4*)out)[(size_t)blockIdx.x * 1024 + i * 256 + threadIdx.x] = z;

  int wave = threadIdx.x >> 6, lane = threadIdx.x & 63;
  int n = blockIdx.x * 4 + wave;
  const float* xr = x + (size_t)n * HDIM;
  float acc[NEXP];
#pragma unroll
  for (int e = 0; e < NEXP; ++e) acc[e] = 0.f;
  float xv[16];
#pragma unroll
  for (int i = 0; i < 16; ++i) {
    int h = lane + 64 * i;
    float v = xr[h];
    xv[i] = v;
#pragma unroll
    for (int e = 0; e < NEXP; ++e) acc[e] += v * rw[e * HDIM + h];
  }
#pragma unroll
  for (int e = 0; e < NEXP; ++e) {
    float v = acc[e];
#pragma unroll
    for (int off = 32; off > 0; off >>= 1) v += __shfl_xor(v, off, 64);
    acc[e] = v;
  }
#pragma unroll
  for (int i = 0; i < 16; ++i)
    xb[(size_t)n * HDIM + lane + 64 * i] = (__bf16)xv[i];

  if (lane == 0) {
    int i1 = 0; float l1 = acc[0];
#pragma unroll
    for (int e = 1; e < NEXP; ++e) if (acc[e] > l1) { l1 = acc[e]; i1 = e; }
    int i2 = -1; float l2 = -3.4e38f;
#pragma unroll
    for (int e = 0; e < NEXP; ++e) if (e != i1 && acc[e] > l2) { l2 = acc[e]; i2 = e; }
    float m = fmaxf(l1, l2);
    float p1 = __expf(l1 - m), p2 = __expf(l2 - m);
    float inv = 1.f / (p1 + p2);
    top_pack[n] = (unsigned int)i1 | ((unsigned int)i2 << 8);
    top_w[n] = make_float2(p1 * inv, p2 * inv);
  }
}

// -------- compact: one block per expert, LDS counter -> counts + tok_list ---------------
__global__ __launch_bounds__(256) void compact_kernel(
    const unsigned int* __restrict__ top_pack,
    int* __restrict__ counts, int* __restrict__ tok_list)
{
  int e = blockIdx.x;
  __shared__ int cnt;
  if (threadIdx.x == 0) cnt = 0;
  __syncthreads();
  for (int n = threadIdx.x; n < NTOK; n += 256) {
    unsigned int p = top_pack[n];
    int e1 = p & 255, e2 = (p >> 8) & 255;
    if (e1 == e) { int pos = atomicAdd(&cnt, 1); tok_list[e * NTOK + pos] = 2 * n; }
    if (e2 == e) { int pos = atomicAdd(&cnt, 1); tok_list[e * NTOK + pos] = 2 * n + 1; }
  }
  __syncthreads();
  if (threadIdx.x == 0) counts[e] = cnt;
}

// -------- gathered GEMM, 256x128x64, 8 waves -- B-RE-READ MINIMIZATION -----------------
// L3-BW model (fits R7/R8/R11): B panel re-read once per M-tile; 128-row tiles => 4
// tiles/expert => up reads 4x64=256MB from L3 (~42us at ~6TB/s ~= the measured 52).
// 256-row tiles halve that (2 tiles/expert). Per-wave work/acc IDENTICAL to R8 (up:
// 32x128, MI=2 NJ=8; down: 64x64, MI=4 NJ=4) -> no spill. LDS 50.2KB static (A single
// buffer) -> 3 blocks/CU. R7's order-independent sync (no counted vmcnt, no R6 hazard):
//   pack B(it) | barrier | ds_write Bs + issue A(it) | vmcnt(0)+lgkmcnt(0) |
//   issue B(it+1) (flies over compute) | barrier | compute
// B staging (512 thr): thread(cB=t>>6, l=t&63) owns k-rows 8cB..8cB+7 x cols {2l,2l+1};
// loads f32x2 (wave-instr: 128 consecutive cols = dense segments). Slot = cB^((r>>1)&7):
// write instr = min 8 cyc (8 lanes/bank-quad, rows distinct); read 2-way (free, m136).
// IS_UP: image rows 0-63 = gate cols, 64-127 = up cols -> SwiGLU in-lane -> hidden.
// !IS_UP: gated fp32 atomicAdd into out (exactly 2 contributions/elem, deterministic).
template<bool IS_UP>
__device__ __forceinline__ void gemm_body(
    const __bf16* __restrict__ Atok, const float* __restrict__ W,
    const int* __restrict__ counts, const int* __restrict__ tok_list,
    __bf16* __restrict__ hidden, float* __restrict__ out,
    const float2* __restrict__ top_w,
    int mb, int n0,
    __bf16* As, __bf16* Bs, int* rows_s)
{
  const int NCS = IS_UP ? 2048 : 1024;   // fp32 source row length
  const int NT = 16;                     // K = 1024, 64 per step
  constexpr int MI = IS_UP ? 2 : 4;      // A fragments per wave
  constexpr int NJ = IS_UP ? 8 : 4;      // B fragments per wave
  int e = -1, m0 = 0, base = 0;
#pragma unroll
  for (int i = 0; i < NEXP; ++i) {
    int c = counts[i];
    int nt = (c + 255) >> 8;
    if (e < 0 && mb < base + nt) { e = i; m0 = (mb - base) << 8; }
    base += nt;
  }
  if (e < 0) return;
  int nrows = counts[e];

  int t = threadIdx.x;
  if (t < 256) {
    int idx = m0 + t;
    rows_s[t] = (idx < nrows) ? tok_list[e * NTOK + idx] : -1;
  }
  __syncthreads();

  int w = t >> 6, lane = t & 63;
  int lm = lane & 15, quad = lane >> 4;
  int rowbase = IS_UP ? (w * 32) : ((w >> 1) * 64);
  int colbase = IS_UP ? 0 : ((w & 1) * 64);

  // A staging pointers: 256 rows x 64k = 2048 chunks of 16B; 4 per thread (512 thr)
  const __bf16* pA[4];
#pragma unroll
  for (int j = 0; j < 4; ++j) {
    int s = j * 512 + t;
    int r = s >> 3;
    int cg = (s & 7) ^ (r & 7);
    int rid = rows_s[r];
    int arow = (rid < 0) ? 0 : (IS_UP ? (rid >> 1) : rid);
    pA[j] = Atok + (size_t)arow * 1024 + cg * 8;
  }

  // B staging: thread owns k-chunk cB (8 k-rows) x cols c0, c0+1
  int cB = t >> 6;            // 0..7 (wave-uniform)
  int c0 = (t & 63) * 2;      // 0..126 (even)
  int csrc = IS_UP ? ((c0 < 64) ? (n0 >> 1) + c0 : 1024 + (n0 >> 1) + (c0 - 64))
                   : n0 + c0;
  const float* Bsrc = W + ((size_t)e * 1024 + cB * 8) * NCS + csrc;
  int slot = cB ^ ((c0 >> 1) & 7);
  int bw0 = c0 * 128 + slot * 16;
  int bw1 = (c0 + 1) * 128 + slot * 16;

  f32x4 acc[MI][NJ];
#pragma unroll
  for (int i = 0; i < MI; ++i)
#pragma unroll
    for (int j = 0; j < NJ; ++j) acc[i][j] = (f32x4){0.f, 0.f, 0.f, 0.f};

  f32x2 v[8];
#pragma unroll
  for (int i = 0; i < 8; ++i)            // prologue: B(0) loads
    v[i] = *(const f32x2*)(Bsrc + (size_t)i * NCS);

  for (int it = 0; it < NT; ++it) {
    // pack B(it): cols c0 and c0+1 (compiler inserts the wait on v here)
    uint4 pk0, pk1;
    {
      union { unsigned int u; __bf16 h[2]; } q[8];
#pragma unroll
      for (int p = 0; p < 4; ++p) {
        q[p].h[0]     = (__bf16)v[2 * p][0];  q[p].h[1]     = (__bf16)v[2 * p + 1][0];
        q[p + 4].h[0] = (__bf16)v[2 * p][1];  q[p + 4].h[1] = (__bf16)v[2 * p + 1][1];
      }
      pk0 = make_uint4(q[0].u, q[1].u, q[2].u, q[3].u);
      pk1 = make_uint4(q[4].u, q[5].u, q[6].u, q[7].u);
    }
    __builtin_amdgcn_s_barrier();        // all waves done reading LDS of step it-1
    __builtin_amdgcn_sched_barrier(0);
    *(uint4*)((char*)Bs + bw0) = pk0;
    *(uint4*)((char*)Bs + bw1) = pk1;
#pragma unroll
    for (int j = 0; j < 4; ++j)          // A(it) -> As (single buffer)
      async_copy16(pA[j] + it * 64, (char*)As + (j * 512 + w * 64) * 16);
    __builtin_amdgcn_sched_barrier(0);
    // order-independent drain: A(it) copies + ds_writes complete
    asm volatile("s_waitcnt vmcnt(0) lgkmcnt(0)" ::: "memory");
    if (it + 1 < NT) {
#pragma unroll
      for (int i = 0; i < 8; ++i)        // B(it+1): issued after drain, flies over MFMA
        v[i] = *(const f32x2*)(Bsrc + (size_t)((it + 1) * 64 + i) * NCS);
    }
    __builtin_amdgcn_sched_barrier(0);
    __builtin_amdgcn_s_barrier();        // stage(it) visible to all waves
    __builtin_amdgcn_sched_barrier(0);

#pragma unroll
    for (int kk = 0; kk < 2; ++kk) {
      bf16x8 a[MI], b[NJ];
#pragma unroll
      for (int i = 0; i < MI; ++i) {
        int R = rowbase + i * 16 + lm;
        int c = (quad + kk * 4) ^ (R & 7);
        a[i] = *(const bf16x8*)((char*)As + (size_t)(R * 8 + c) * 16);
      }
#pragma unroll
      for (int j = 0; j < NJ; ++j) {
        int R = colbase + j * 16 + lm;
        int c = (quad + kk * 4) ^ ((R >> 1) & 7);
        b[j] = *(const bf16x8*)((char*)Bs + (size_t)(R * 8 + c) * 16);
      }
#pragma unroll
      for (int i = 0; i < MI; ++i)
#pragma unroll
        for (int j = 0; j < NJ; ++j)
          acc[i][j] = mfma16(a[i], b[j], acc[i][j]);
    }
  }

  if (IS_UP) {
    int dbase = n0 >> 1;   // 64 unique d per 128-wide tile
#pragma unroll
    for (int i = 0; i < MI; ++i)
#pragma unroll
      for (int r = 0; r < 4; ++r) {
        int lr = rowbase + i * 16 + quad * 4 + r;    // C/D: row = quad*4+reg
        int rid = rows_s[lr];
        if (rid >= 0) {
#pragma unroll
          for (int j = 0; j < 4; ++j) {
            float g = acc[i][j][r];
            float u = acc[i][j + 4][r];
            float hv = g / (1.f + __expf(-g)) * u;
            hidden[(size_t)rid * DDIM + dbase + j * 16 + lm] = (__bf16)hv;
          }
        }
      }
  } else {
#pragma unroll
    for (int i = 0; i < MI; ++i)
#pragma unroll
      for (int r = 0; r < 4; ++r) {
        int lr = rowbase + i * 16 + quad * 4 + r;
        int rid = rows_s[lr];
        if (rid >= 0) {
          float2 tw = top_w[rid >> 1];
          float wt = (rid & 1) ? tw.y : tw.x;
          float* orow = out + (size_t)(rid >> 1) * HDIM + n0 + colbase;
#pragma unroll
          for (int j = 0; j < NJ; ++j)
            atomicAdd(orow + j * 16 + lm, acc[i][j][r] * wt);
        }
      }
  }
}

// -------- up-GEMM: 384 blocks (16 ny x 24 mb), ny fastest -> XCD spread ----------------
__global__ __launch_bounds__(512, 4) void up_kernel(
    const __bf16* __restrict__ xb, const float* __restrict__ wup,
    const int* __restrict__ counts, const int* __restrict__ tok_list,
    __bf16* __restrict__ hidden)
{
  __shared__ __align__(16) char smem[50176];   // As 32K | Bs 16K | rows_s 1K
  __bf16* As = (__bf16*)smem;
  __bf16* Bs = (__bf16*)(smem + 32768);
  int* rows_s = (int*)(smem + 49152);
  int b = blockIdx.x;
  gemm_body<true>(xb, wup, counts, tok_list, hidden, (float*)nullptr,
                  (const float2*)nullptr, b >> 4, (b & 15) * 128, As, Bs, rows_s);
}

// -------- down: 192 blocks (8 ny x 24 mb), 2 atomic contributions/elem -----------------
__global__ __launch_bounds__(512, 4) void down_kernel(
    const __bf16* __restrict__ hidden, const float* __restrict__ wdn,
    const int* __restrict__ counts, const int* __restrict__ tok_list,
    const float2* __restrict__ top_w, float* __restrict__ out)
{
  __shared__ __align__(16) char smem[50176];
  __bf16* As = (__bf16*)smem;
  __bf16* Bs = (__bf16*)(smem + 32768);
  int* rows_s = (int*)(smem + 49152);
  int b = blockIdx.x;
  gemm_body<false>(hidden, wdn, counts, tok_list, (__bf16*)nullptr, out, top_w,
                   b >> 3, (b & 7) * 128, As, Bs, rows_s);
}

extern "C" void kernel_launch(void* const* d_in, const int* in_sizes, int n_in,
                              void* d_out, int out_size, void* d_ws, size_t ws_size,
                              hipStream_t stream) {
  const float* x  = (const float*)d_in[0];
  const float* rw = (const float*)d_in[1];
  const float* up = (const float*)d_in[2];
  const float* dw = (const float*)d_in[3];
  float* out = (float*)d_out;

  char* ws = (char*)d_ws;
  int* counts          = (int*)ws;                             // 32 B
  int* tok_list        = (int*)(ws + 4096);                    // 64 KB
  unsigned int* top_pk = (unsigned int*)(ws + (256u << 10));   // 8 KB  @ 256 KB
  float2* top_w        = (float2*)(ws + (272u << 10));         // 16 KB @ 272 KB
  __bf16* xb           = (__bf16*)(ws + (1u << 20));           // 4 MB  @ 1 MB
  __bf16* hidden       = (__bf16*)(ws + (8u << 20));           // 8 MB  @ 8 MB
  (void)ws_size; (void)n_in; (void)in_sizes; (void)out_size;

  setup_kernel<<<NTOK / 4, 256, 0, stream>>>(x, rw, xb, top_pk, top_w, out);
  compact_kernel<<<NEXP, 256, 0, stream>>>(top_pk, counts, tok_list);
  up_kernel<<<16 * MBT, 512, 0, stream>>>(xb, up, counts, tok_list, hidden);
  down_kernel<<<8 * MBT, 512, 0, stream>>>(
      hidden, dw, counts, tok_list, top_w, out);
}

// Round 15
// 228.601 us; speedup vs baseline: 1.0422x; 1.0422x over previous
//
#include <hip/hip_runtime.h>
#include <hip/hip_bf16.h>

#define NTOK 2048
#define HDIM 1024
#define DDIM 1024
#define NEXP 8
#define MBT 24   // max M-tiles: sum ceil(c_e/256) <= 16 + 7 = 23

typedef __bf16 bf16x8 __attribute__((ext_vector_type(8)));
typedef float f32x4 __attribute__((ext_vector_type(4)));
typedef float f32x2 __attribute__((ext_vector_type(2)));

__device__ __forceinline__ f32x4 mfma16(bf16x8 a, bf16x8 b, f32x4 c) {
  return __builtin_amdgcn_mfma_f32_16x16x32_bf16(a, b, c, 0, 0, 0);
}

__device__ __forceinline__ void async_copy16(const void* g, void* l) {
  __builtin_amdgcn_global_load_lds(
      (const __attribute__((address_space(1))) void*)g,
      (__attribute__((address_space(3))) void*)l, 16, 0, 0);
}

// -------- setup: router + zero `out` (for down's atomic combine). 512 blocks. ----------
__global__ __launch_bounds__(256) void setup_kernel(
    const float* __restrict__ x, const float* __restrict__ rw,
    __bf16* __restrict__ xb,
    unsigned int* __restrict__ top_pack, float2* __restrict__ top_w,
    float* __restrict__ out)
{
  f32x4 z = (f32x4){0.f, 0.f, 0.f, 0.f};
#pragma unroll
  for (int i = 0; i < 4; ++i)
    ((f32x4*)out)[(size_t)blockIdx.x * 1024 + i * 256 + threadIdx.x] = z;

  int wave = threadIdx.x >> 6, lane = threadIdx.x & 63;
  int n = blockIdx.x * 4 + wave;
  const float* xr = x + (size_t)n * HDIM;
  float acc[NEXP];
#pragma unroll
  for (int e = 0; e < NEXP; ++e) acc[e] = 0.f;
  float xv[16];
#pragma unroll
  for (int i = 0; i < 16; ++i) {
    int h = lane + 64 * i;
    float v = xr[h];
    xv[i] = v;
#pragma unroll
    for (int e = 0; e < NEXP; ++e) acc[e] += v * rw[e * HDIM + h];
  }
#pragma unroll
  for (int e = 0; e < NEXP; ++e) {
    float v = acc[e];
#pragma unroll
    for (int off = 32; off > 0; off >>= 1) v += __shfl_xor(v, off, 64);
    acc[e] = v;
  }
#pragma unroll
  for (int i = 0; i < 16; ++i)
    xb[(size_t)n * HDIM + lane + 64 * i] = (__bf16)xv[i];

  if (lane == 0) {
    int i1 = 0; float l1 = acc[0];
#pragma unroll
    for (int e = 1; e < NEXP; ++e) if (acc[e] > l1) { l1 = acc[e]; i1 = e; }
    int i2 = -1; float l2 = -3.4e38f;
#pragma unroll
    for (int e = 0; e < NEXP; ++e) if (e != i1 && acc[e] > l2) { l2 = acc[e]; i2 = e; }
    float m = fmaxf(l1, l2);
    float p1 = __expf(l1 - m), p2 = __expf(l2 - m);
    float inv = 1.f / (p1 + p2);
    top_pack[n] = (unsigned int)i1 | ((unsigned int)i2 << 8);
    top_w[n] = make_float2(p1 * inv, p2 * inv);
  }
}

// -------- compact: one block per expert, LDS counter -> counts + tok_list ---------------
__global__ __launch_bounds__(256) void compact_kernel(
    const unsigned int* __restrict__ top_pack,
    int* __restrict__ counts, int* __restrict__ tok_list)
{
  int e = blockIdx.x;
  __shared__ int cnt;
  if (threadIdx.x == 0) cnt = 0;
  __syncthreads();
  for (int n = threadIdx.x; n < NTOK; n += 256) {
    unsigned int p = top_pack[n];
    int e1 = p & 255, e2 = (p >> 8) & 255;
    if (e1 == e) { int pos = atomicAdd(&cnt, 1); tok_list[e * NTOK + pos] = 2 * n; }
    if (e2 == e) { int pos = atomicAdd(&cnt, 1); tok_list[e * NTOK + pos] = 2 * n + 1; }
  }
  __syncthreads();
  if (threadIdx.x == 0) counts[e] = cnt;
}

// -------- gathered GEMM, 256x128x64, 8 waves -- B-RE-READ MINIMIZATION (clean retest) --
// R14's run was confounded: launch_bounds(512,4) capped VGPR at 64 -> acc spilled
// (WRITE_SIZE 36MB). This round: launch_bounds(512,1) -> compiler free (~120 VGPR),
// occupancy LDS-bound at 3 blocks/CU (24 waves/CU, same as R8). Everything else
// identical to R14, so the L3 model finally gets a clean test: B panel re-read once
// per M-tile; 256-row tiles => 2 tiles/expert => up B traffic 128MB (vs R8's 256MB).
// Sync (R7-style, order-independent):
//   pack B(it) | barrier | ds_write Bs + issue A(it) | vmcnt(0)+lgkmcnt(0) |
//   issue B(it+1) (flies over compute) | barrier | compute
// B staging (512 thr): thread(cB=t>>6, l=t&63) owns k-rows 8cB..8cB+7 x cols {2l,2l+1};
// slot = cB^((r>>1)&7): write = min 8 cyc/bank, read 2-way (free, m136).
// IS_UP: image rows 0-63 = gate cols, 64-127 = up cols -> SwiGLU in-lane -> hidden.
// !IS_UP: gated fp32 atomicAdd into out (exactly 2 contributions/elem, deterministic).
template<bool IS_UP>
__device__ __forceinline__ void gemm_body(
    const __bf16* __restrict__ Atok, const float* __restrict__ W,
    const int* __restrict__ counts, const int* __restrict__ tok_list,
    __bf16* __restrict__ hidden, float* __restrict__ out,
    const float2* __restrict__ top_w,
    int mb, int n0,
    __bf16* As, __bf16* Bs, int* rows_s)
{
  const int NCS = IS_UP ? 2048 : 1024;   // fp32 source row length
  const int NT = 16;                     // K = 1024, 64 per step
  constexpr int MI = IS_UP ? 2 : 4;      // A fragments per wave
  constexpr int NJ = IS_UP ? 8 : 4;      // B fragments per wave
  int e = -1, m0 = 0, base = 0;
#pragma unroll
  for (int i = 0; i < NEXP; ++i) {
    int c = counts[i];
    int nt = (c + 255) >> 8;
    if (e < 0 && mb < base + nt) { e = i; m0 = (mb - base) << 8; }
    base += nt;
  }
  if (e < 0) return;
  int nrows = counts[e];

  int t = threadIdx.x;
  if (t < 256) {
    int idx = m0 + t;
    rows_s[t] = (idx < nrows) ? tok_list[e * NTOK + idx] : -1;
  }
  __syncthreads();

  int w = t >> 6, lane = t & 63;
  int lm = lane & 15, quad = lane >> 4;
  int rowbase = IS_UP ? (w * 32) : ((w >> 1) * 64);
  int colbase = IS_UP ? 0 : ((w & 1) * 64);

  // A staging pointers: 256 rows x 64k = 2048 chunks of 16B; 4 per thread (512 thr)
  const __bf16* pA[4];
#pragma unroll
  for (int j = 0; j < 4; ++j) {
    int s = j * 512 + t;
    int r = s >> 3;
    int cg = (s & 7) ^ (r & 7);
    int rid = rows_s[r];
    int arow = (rid < 0) ? 0 : (IS_UP ? (rid >> 1) : rid);
    pA[j] = Atok + (size_t)arow * 1024 + cg * 8;
  }

  // B staging: thread owns k-chunk cB (8 k-rows) x cols c0, c0+1
  int cB = t >> 6;            // 0..7 (wave-uniform)
  int c0 = (t & 63) * 2;      // 0..126 (even)
  int csrc = IS_UP ? ((c0 < 64) ? (n0 >> 1) + c0 : 1024 + (n0 >> 1) + (c0 - 64))
                   : n0 + c0;
  const float* Bsrc = W + ((size_t)e * 1024 + cB * 8) * NCS + csrc;
  int slot = cB ^ ((c0 >> 1) & 7);
  int bw0 = c0 * 128 + slot * 16;
  int bw1 = (c0 + 1) * 128 + slot * 16;

  f32x4 acc[MI][NJ];
#pragma unroll
  for (int i = 0; i < MI; ++i)
#pragma unroll
    for (int j = 0; j < NJ; ++j) acc[i][j] = (f32x4){0.f, 0.f, 0.f, 0.f};

  f32x2 v[8];
#pragma unroll
  for (int i = 0; i < 8; ++i)            // prologue: B(0) loads
    v[i] = *(const f32x2*)(Bsrc + (size_t)i * NCS);

  for (int it = 0; it < NT; ++it) {
    // pack B(it): cols c0 and c0+1 (compiler inserts the wait on v here)
    uint4 pk0, pk1;
    {
      union { unsigned int u; __bf16 h[2]; } q[8];
#pragma unroll
      for (int p = 0; p < 4; ++p) {
        q[p].h[0]     = (__bf16)v[2 * p][0];  q[p].h[1]     = (__bf16)v[2 * p + 1][0];
        q[p + 4].h[0] = (__bf16)v[2 * p][1];  q[p + 4].h[1] = (__bf16)v[2 * p + 1][1];
      }
      pk0 = make_uint4(q[0].u, q[1].u, q[2].u, q[3].u);
      pk1 = make_uint4(q[4].u, q[5].u, q[6].u, q[7].u);
    }
    __builtin_amdgcn_s_barrier();        // all waves done reading LDS of step it-1
    __builtin_amdgcn_sched_barrier(0);
    *(uint4*)((char*)Bs + bw0) = pk0;
    *(uint4*)((char*)Bs + bw1) = pk1;
#pragma unroll
    for (int j = 0; j < 4; ++j)          // A(it) -> As (single buffer)
      async_copy16(pA[j] + it * 64, (char*)As + (j * 512 + w * 64) * 16);
    __builtin_amdgcn_sched_barrier(0);
    // order-independent drain: A(it) copies + ds_writes complete
    asm volatile("s_waitcnt vmcnt(0) lgkmcnt(0)" ::: "memory");
    if (it + 1 < NT) {
#pragma unroll
      for (int i = 0; i < 8; ++i)        // B(it+1): issued after drain, flies over MFMA
        v[i] = *(const f32x2*)(Bsrc + (size_t)((it + 1) * 64 + i) * NCS);
    }
    __builtin_amdgcn_sched_barrier(0);
    __builtin_amdgcn_s_barrier();        // stage(it) visible to all waves
    __builtin_amdgcn_sched_barrier(0);

#pragma unroll
    for (int kk = 0; kk < 2; ++kk) {
      bf16x8 a[MI], b[NJ];
#pragma unroll
      for (int i = 0; i < MI; ++i) {
        int R = rowbase + i * 16 + lm;
        int c = (quad + kk * 4) ^ (R & 7);
        a[i] = *(const bf16x8*)((char*)As + (size_t)(R * 8 + c) * 16);
      }
#pragma unroll
      for (int j = 0; j < NJ; ++j) {
        int R = colbase + j * 16 + lm;
        int c = (quad + kk * 4) ^ ((R >> 1) & 7);
        b[j] = *(const bf16x8*)((char*)Bs + (size_t)(R * 8 + c) * 16);
      }
#pragma unroll
      for (int i = 0; i < MI; ++i)
#pragma unroll
        for (int j = 0; j < NJ; ++j)
          acc[i][j] = mfma16(a[i], b[j], acc[i][j]);
    }
  }

  if (IS_UP) {
    int dbase = n0 >> 1;   // 64 unique d per 128-wide tile
#pragma unroll
    for (int i = 0; i < MI; ++i)
#pragma unroll
      for (int r = 0; r < 4; ++r) {
        int lr = rowbase + i * 16 + quad * 4 + r;    // C/D: row = quad*4+reg
        int rid = rows_s[lr];
        if (rid >= 0) {
#pragma unroll
          for (int j = 0; j < 4; ++j) {
            float g = acc[i][j][r];
            float u = acc[i][j + 4][r];
            float hv = g / (1.f + __expf(-g)) * u;
            hidden[(size_t)rid * DDIM + dbase + j * 16 + lm] = (__bf16)hv;
          }
        }
      }
  } else {
#pragma unroll
    for (int i = 0; i < MI; ++i)
#pragma unroll
      for (int r = 0; r < 4; ++r) {
        int lr = rowbase + i * 16 + quad * 4 + r;
        int rid = rows_s[lr];
        if (rid >= 0) {
          float2 tw = top_w[rid >> 1];
          float wt = (rid & 1) ? tw.y : tw.x;
          float* orow = out + (size_t)(rid >> 1) * HDIM + n0 + colbase;
#pragma unroll
          for (int j = 0; j < NJ; ++j)
            atomicAdd(orow + j * 16 + lm, acc[i][j][r] * wt);
        }
      }
  }
}

// -------- up-GEMM: 384 blocks (16 ny x 24 mb), ny fastest -> XCD spread ----------------
__global__ __launch_bounds__(512, 1) void up_kernel(
    const __bf16* __restrict__ xb, const float* __restrict__ wup,
    const int* __restrict__ counts, const int* __restrict__ tok_list,
    __bf16* __restrict__ hidden)
{
  __shared__ __align__(16) char smem[50176];   // As 32K | Bs 16K | rows_s 1K
  __bf16* As = (__bf16*)smem;
  __bf16* Bs = (__bf16*)(smem + 32768);
  int* rows_s = (int*)(smem + 49152);
  int b = blockIdx.x;
  gemm_body<true>(xb, wup, counts, tok_list, hidden, (float*)nullptr,
                  (const float2*)nullptr, b >> 4, (b & 15) * 128, As, Bs, rows_s);
}

// -------- down: 192 blocks (8 ny x 24 mb), 2 atomic contributions/elem -----------------
__global__ __launch_bounds__(512, 1) void down_kernel(
    const __bf16* __restrict__ hidden, const float* __restrict__ wdn,
    const int* __restrict__ counts, const int* __restrict__ tok_list,
    const float2* __restrict__ top_w, float* __restrict__ out)
{
  __shared__ __align__(16) char smem[50176];
  __bf16* As = (__bf16*)smem;
  __bf16* Bs = (__bf16*)(smem + 32768);
  int* rows_s = (int*)(smem + 49152);
  int b = blockIdx.x;
  gemm_body<false>(hidden, wdn, counts, tok_list, (__bf16*)nullptr, out, top_w,
                   b >> 3, (b & 7) * 128, As, Bs, rows_s);
}

extern "C" void kernel_launch(void* const* d_in, const int* in_sizes, int n_in,
                              void* d_out, int out_size, void* d_ws, size_t ws_size,
                              hipStream_t stream) {
  const float* x  = (const float*)d_in[0];
  const float* rw = (const float*)d_in[1];
  const float* up = (const float*)d_in[2];
  const float* dw = (const float*)d_in[3];
  float* out = (float*)d_out;

  char* ws = (char*)d_ws;
  int* counts          = (int*)ws;                             // 32 B
  int* tok_list        = (int*)(ws + 4096);                    // 64 KB
  unsigned int* top_pk = (unsigned int*)(ws + (256u << 10));   // 8 KB  @ 256 KB
  float2* top_w        = (float2*)(ws + (272u << 10));         // 16 KB @ 272 KB
  __bf16* xb           = (__bf16*)(ws + (1u << 20));           // 4 MB  @ 1 MB
  __bf16* hidden       = (__bf16*)(ws + (8u << 20));           // 8 MB  @ 8 MB
  (void)ws_size; (void)n_in; (void)in_sizes; (void)out_size;

  setup_kernel<<<NTOK / 4, 256, 0, stream>>>(x, rw, xb, top_pk, top_w, out);
  compact_kernel<<<NEXP, 256, 0, stream>>>(top_pk, counts, tok_list);
  up_kernel<<<16 * MBT, 512, 0, stream>>>(xb, up, counts, tok_list, hidden);
  down_kernel<<<8 * MBT, 512, 0, stream>>>(
      hidden, dw, counts, tok_list, top_w, out);
}